// Round 3
// baseline (1107.223 us; speedup 1.0000x reference)
//
#include <hip/hip_runtime.h>
#include <hip/hip_bf16.h>

typedef __attribute__((ext_vector_type(8))) short bf16x8;
typedef __attribute__((ext_vector_type(4))) float f32x4;
typedef unsigned short u16;
typedef unsigned int u32;

#define NN 1024
#define ETOT 523776
#define EPSV 1e-5f

// LDS layout (bytes) — scalars at low offsets, big tiles high, no aliasing
#define L_PSUM   0        /* 512*4  = 2048 */
#define L_PSQ    2048     /* 2048 */
#define L_MU     4096     /* 256  */
#define L_SINV   4352     /* 256  */
#define L_B1     4608     /* 2048 */
#define L_GM     6656     /* 2048 */
#define L_BT     8704     /* 2048 */
#define L_B2     10752    /* 1024 */
#define L_W3     11776    /* 1024 */
#define L_A1     12800    /* 64*264*2 = 33792 */
#define L_H1N    46592    /* 64*520*2 = 66560 */
#define L_TOTAL  113152

__device__ __forceinline__ u16 f2bf(float f) {
  union { float f; u32 u; } v; v.f = f;
  u32 r = v.u + 0x7FFFu + ((v.u >> 16) & 1u);   // RNE, finite inputs only
  return (u16)(r >> 16);
}

// ---- prep: W1^T [512][256] bf16 and W2^T [256][512] bf16 ----
__global__ void prep_wt(const float* __restrict__ W1, const float* __restrict__ W2,
                        u16* __restrict__ W1t, u16* __restrict__ W2t) {
  int idx = blockIdx.x * 256 + threadIdx.x;      // [0, 131072)
  { int n = idx >> 8, k = idx & 255; W1t[idx] = f2bf(W1[k*512 + n]); }
  { int n = idx >> 9, k = idx & 511; W2t[idx] = f2bf(W2[k*256 + n]); }
}

// ---- pairs: trivial, independent of the edge kernel (f32 output!) ----
__global__ void pairs_kernel(float* __restrict__ out) {
  int i = blockIdx.x;                            // 0..1023
  int j = i + 1 + blockIdx.y * 256 + threadIdx.x;
  if (j >= NN) return;
  int e = i*(2*NN - i - 1)/2 + (j - i - 1);
  out[ETOT + 2*e]     = (float)i;
  out[ETOT + 2*e + 1] = (float)j;
}

// ---- main fused kernel: block (bj,bi) = 8x8 node tile = 64 edges ----
__launch_bounds__(512, 2)
__global__ void edge_main(const float* __restrict__ emb,
                          const float* __restrict__ b1v,
                          const float* __restrict__ gammav,
                          const float* __restrict__ betav,
                          const float* __restrict__ b2v,
                          const float* __restrict__ w3v,
                          const float* __restrict__ b3v,
                          const u16* __restrict__ W1t,
                          const u16* __restrict__ W2t,
                          float* __restrict__ out) {
  const int bi = blockIdx.y, bj = blockIdx.x;
  if (bj < bi) return;                           // lower triangle: nothing to do
  const int i0 = bi*8, j0 = bj*8;

  extern __shared__ char smem[];
  float* psum = (float*)(smem + L_PSUM);
  float* psq  = (float*)(smem + L_PSQ);
  float* smu  = (float*)(smem + L_MU);
  float* ssin = (float*)(smem + L_SINV);
  float* sb1  = (float*)(smem + L_B1);
  float* sgm  = (float*)(smem + L_GM);
  float* sbt  = (float*)(smem + L_BT);
  float* sb2  = (float*)(smem + L_B2);
  float* sw3  = (float*)(smem + L_W3);
  u16*   A1   = (u16*)(smem + L_A1);             // [64][264], cols 0..255 used
  u16*   h1n  = (u16*)(smem + L_H1N);            // [64][520], cols 0..511 used

  const int tid  = threadIdx.x;
  const int wave = tid >> 6;
  const int lane = tid & 63;
  const int llo  = lane & 15;
  const int lhi  = lane >> 4;

  // ---- stage A1 = [e_i - e_j | e_i * e_j] (bf16) ----
  {
    int t  = tid >> 3;                 // edge row 0..63 ; a = t/8 (i), b = t%8 (j)
    int a  = t >> 3, b = t & 7;
    int c0 = (tid & 7) * 32;           // 32 cols of the 256-wide feature row
    u16* dst = A1 + t*264 + c0;
    if (c0 < 128) {
      const float4* ei = (const float4*)(emb + (i0 + a)*128 + c0);
      const float4* ej = (const float4*)(emb + (j0 + b)*128 + c0);
      #pragma unroll
      for (int q = 0; q < 8; ++q) {
        float4 x = ei[q], y = ej[q];
        u32 lo = (u32)f2bf(x.x - y.x) | ((u32)f2bf(x.y - y.y) << 16);
        u32 hi = (u32)f2bf(x.z - y.z) | ((u32)f2bf(x.w - y.w) << 16);
        *(uint2*)(dst + q*4) = make_uint2(lo, hi);
      }
    } else {
      const float4* ei = (const float4*)(emb + (i0 + a)*128 + (c0 - 128));
      const float4* ej = (const float4*)(emb + (j0 + b)*128 + (c0 - 128));
      #pragma unroll
      for (int q = 0; q < 8; ++q) {
        float4 x = ei[q], y = ej[q];
        u32 lo = (u32)f2bf(x.x * y.x) | ((u32)f2bf(x.y * y.y) << 16);
        u32 hi = (u32)f2bf(x.z * y.z) | ((u32)f2bf(x.w * y.w) << 16);
        *(uint2*)(dst + q*4) = make_uint2(lo, hi);
      }
    }
  }
  sb1[tid] = b1v[tid];
  sgm[tid] = gammav[tid];
  sbt[tid] = betav[tid];
  if (tid < 256) { sb2[tid] = b2v[tid]; sw3[tid] = w3v[tid]; }
  __syncthreads();

  // ---- GEMM1: A1[64x256] @ W1[256x512]; wave owns 64-col stripe ----
  f32x4 acc1[4][4];
  #pragma unroll
  for (int m = 0; m < 4; ++m)
    #pragma unroll
    for (int n = 0; n < 4; ++n)
      acc1[m][n] = (f32x4){0.f, 0.f, 0.f, 0.f};

  #pragma unroll
  for (int kb = 0; kb < 8; ++kb) {
    bf16x8 af[4], bfr[4];
    #pragma unroll
    for (int m = 0; m < 4; ++m)
      af[m] = *(const bf16x8*)(A1 + (m*16 + llo)*264 + kb*32 + lhi*8);
    #pragma unroll
    for (int n = 0; n < 4; ++n)
      bfr[n] = *(const bf16x8*)(W1t + (wave*64 + n*16 + llo)*256 + kb*32 + lhi*8);
    #pragma unroll
    for (int m = 0; m < 4; ++m)
      #pragma unroll
      for (int n = 0; n < 4; ++n)
        acc1[m][n] = __builtin_amdgcn_mfma_f32_16x16x32_bf16(af[m], bfr[n], acc1[m][n], 0, 0, 0);
  }

  // ---- epilogue1: +b1, relu, LN partial stats ----
  #pragma unroll
  for (int m = 0; m < 4; ++m) {
    #pragma unroll
    for (int q = 0; q < 4; ++q) {
      int r = m*16 + lhi*4 + q;
      float sum = 0.f, sq = 0.f;
      #pragma unroll
      for (int n = 0; n < 4; ++n) {
        int col = wave*64 + n*16 + llo;
        float v = acc1[m][n][q] + sb1[col];
        v = fmaxf(v, 0.f);
        acc1[m][n][q] = v;
        sum += v;
        sq  += v*v;
      }
      #pragma unroll
      for (int off = 1; off < 16; off <<= 1) {
        sum += __shfl_xor(sum, off, 64);
        sq  += __shfl_xor(sq,  off, 64);
      }
      if (llo == 0) { psum[r*8 + wave] = sum; psq[r*8 + wave] = sq; }
    }
  }
  __syncthreads();
  if (tid < 64) {
    float s = 0.f, ss = 0.f;
    #pragma unroll
    for (int w = 0; w < 8; ++w) { s += psum[tid*8 + w]; ss += psq[tid*8 + w]; }
    float mu  = s * (1.f/512.f);
    float var = ss * (1.f/512.f) - mu*mu;
    smu[tid]  = mu;
    ssin[tid] = rsqrtf(var + EPSV);
  }
  __syncthreads();

  // ---- normalize -> h1n bf16 in LDS ----
  #pragma unroll
  for (int m = 0; m < 4; ++m) {
    #pragma unroll
    for (int q = 0; q < 4; ++q) {
      int r = m*16 + lhi*4 + q;
      float mu = smu[r], si = ssin[r];
      #pragma unroll
      for (int n = 0; n < 4; ++n) {
        int col = wave*64 + n*16 + llo;
        float v = (acc1[m][n][q] - mu) * si * sgm[col] + sbt[col];
        h1n[r*520 + col] = f2bf(v);
      }
    }
  }
  __syncthreads();

  // ---- GEMM2: h1n[64x512] @ W2[512x256]; wave owns 32-col stripe ----
  f32x4 acc2[4][2];
  #pragma unroll
  for (int m = 0; m < 4; ++m) { acc2[m][0] = (f32x4){0,0,0,0}; acc2[m][1] = (f32x4){0,0,0,0}; }

  #pragma unroll 4
  for (int kb = 0; kb < 16; ++kb) {
    bf16x8 af[4], bfr[2];
    #pragma unroll
    for (int m = 0; m < 4; ++m)
      af[m] = *(const bf16x8*)(h1n + (m*16 + llo)*520 + kb*32 + lhi*8);
    #pragma unroll
    for (int n = 0; n < 2; ++n)
      bfr[n] = *(const bf16x8*)(W2t + (wave*32 + n*16 + llo)*512 + kb*32 + lhi*8);
    #pragma unroll
    for (int m = 0; m < 4; ++m)
      #pragma unroll
      for (int n = 0; n < 2; ++n)
        acc2[m][n] = __builtin_amdgcn_mfma_f32_16x16x32_bf16(af[m], bfr[n], acc2[m][n], 0, 0, 0);
  }

  // ---- epilogue2: +b2, relu, dot W3, reduce per row ----
  #pragma unroll
  for (int m = 0; m < 4; ++m) {
    #pragma unroll
    for (int q = 0; q < 4; ++q) {
      int r = m*16 + lhi*4 + q;
      float s = 0.f;
      #pragma unroll
      for (int n = 0; n < 2; ++n) {
        int col = wave*32 + n*16 + llo;
        float v = acc2[m][n][q] + sb2[col];
        v = fmaxf(v, 0.f);
        s += v * sw3[col];
      }
      #pragma unroll
      for (int off = 1; off < 16; off <<= 1) s += __shfl_xor(s, off, 64);
      if (llo == 0) psum[r*8 + wave] = s;
    }
  }
  __syncthreads();
  if (tid < 64) {
    float s = 0.f;
    #pragma unroll
    for (int w = 0; w < 8; ++w) s += psum[tid*8 + w];
    float logit = s + b3v[0];
    int a = tid >> 3, b = tid & 7;
    int i = i0 + a, j = j0 + b;
    if (i < j) {
      int eidx = i*(2*NN - i - 1)/2 + (j - i - 1);
      out[eidx] = logit;                 // f32 output
    }
  }
}

extern "C" void kernel_launch(void* const* d_in, const int* in_sizes, int n_in,
                              void* d_out, int out_size, void* d_ws, size_t ws_size,
                              hipStream_t stream) {
  const float* emb   = (const float*)d_in[0];
  const float* W1    = (const float*)d_in[1];
  const float* b1    = (const float*)d_in[2];
  const float* gamma = (const float*)d_in[3];
  const float* beta  = (const float*)d_in[4];
  const float* W2    = (const float*)d_in[5];
  const float* b2    = (const float*)d_in[6];
  const float* W3    = (const float*)d_in[7];
  const float* b3    = (const float*)d_in[8];

  char* ws  = (char*)d_ws;
  u16* W1t = (u16*)ws;                       // 512*256*2 = 256 KiB
  u16* W2t = (u16*)(ws + 512*256*2);         // 256*512*2 = 256 KiB

  (void)hipFuncSetAttribute((const void*)edge_main,
                            hipFuncAttributeMaxDynamicSharedMemorySize, L_TOTAL);

  prep_wt<<<512, 256, 0, stream>>>(W1, W2, W1t, W2t);
  pairs_kernel<<<dim3(1024, 4), 256, 0, stream>>>((float*)d_out);
  edge_main<<<dim3(128, 128), 512, L_TOTAL, stream>>>(emb, b1, gamma, beta, b2, W3, b3,
                                                      W1t, W2t, (float*)d_out);
}

// Round 4
// 690.386 us; speedup vs baseline: 1.6038x; 1.6038x over previous
//
#include <hip/hip_runtime.h>

typedef __attribute__((ext_vector_type(8))) short bf16x8;
typedef __attribute__((ext_vector_type(4))) float f32x4;
typedef unsigned short u16;
typedef unsigned int u32;

#define NN 1024
#define ETOT 523776
#define EPSV 1e-5f

// LDS layout (bytes)
#define L_PSUM  0        /* 512*4 = 2048 */
#define L_PSQ   2048     /* 2048 */
#define L_MU    4096     /* 256  */
#define L_SINV  4352     /* 256  */
#define L_B1    4608     /* 2048 */
#define L_GM    6656     /* 2048 */
#define L_BT    8704     /* 2048 */
#define L_B2    10752    /* 1024 */
#define L_W3    11776    /* 1024 */
#define L_TILE  12800    /* 64 KiB: A1 [64][256]bf16 (swz) aliased with h1n [64][512]bf16 (swz) */
#define L_TOTAL 78336    /* 2 blocks/CU: 156672 <= 163840 */

__device__ __forceinline__ u16 f2bf(float f) {
  union { float f; u32 u; } v; v.f = f;
  u32 r = v.u + 0x7FFFu + ((v.u >> 16) & 1u);   // RNE, finite inputs only
  return (u16)(r >> 16);
}

// ---- prep: W1^T [512][256] bf16 and W2^T [256][512] bf16 ----
__global__ void prep_wt(const float* __restrict__ W1, const float* __restrict__ W2,
                        u16* __restrict__ W1t, u16* __restrict__ W2t) {
  int idx = blockIdx.x * 256 + threadIdx.x;      // [0, 131072)
  { int n = idx >> 8, k = idx & 255; W1t[idx] = f2bf(W1[k*512 + n]); }
  { int n = idx >> 9, k = idx & 511; W2t[idx] = f2bf(W2[k*256 + n]); }
}

// ---- main fused kernel: one block = 8x8 node tile = 64 edge rows ----
__launch_bounds__(512, 4)
__global__ void edge_main(const float* __restrict__ emb,
                          const float* __restrict__ b1v,
                          const float* __restrict__ gammav,
                          const float* __restrict__ betav,
                          const float* __restrict__ b2v,
                          const float* __restrict__ w3v,
                          const float* __restrict__ b3v,
                          const u16* __restrict__ W1t,
                          const u16* __restrict__ W2t,
                          float* __restrict__ out) {
  // exact upper-triangle (incl. diagonal) tile mapping: 8256 blocks
  int kblk = blockIdx.x;
  int bi = (int)((257.0f - sqrtf(66049.0f - 8.0f*(float)kblk)) * 0.5f);
  bi = bi < 0 ? 0 : (bi > 127 ? 127 : bi);
  while (bi*128 - bi*(bi-1)/2 > kblk) --bi;
  while ((bi+1)*128 - (bi+1)*bi/2 <= kblk) ++bi;
  const int bj = bi + (kblk - (bi*128 - bi*(bi-1)/2));
  const int i0 = bi*8, j0 = bj*8;

  extern __shared__ char smem[];
  float* psum = (float*)(smem + L_PSUM);
  float* psq  = (float*)(smem + L_PSQ);
  float* smu  = (float*)(smem + L_MU);
  float* ssin = (float*)(smem + L_SINV);
  float* sb1  = (float*)(smem + L_B1);
  float* sgm  = (float*)(smem + L_GM);
  float* sbt  = (float*)(smem + L_BT);
  float* sb2  = (float*)(smem + L_B2);
  float* sw3  = (float*)(smem + L_W3);
  char*  tile = smem + L_TILE;

  const int tid  = threadIdx.x;
  const int wave = tid >> 6;
  const int lane = tid & 63;
  const int llo  = lane & 15;
  const int lhi  = lane >> 4;
  const int sw   = (llo & 7) << 4;     // XOR-swizzle slot for af reads

  // ---- stage A1 = [e_i - e_j | e_i * e_j] bf16, XOR-swizzled [64][256] (512B rows) ----
  {
    int t  = tid >> 3, cg = tid & 7;
    int a  = t >> 3, b = t & 7;
    const float* ei = emb + (i0 + a)*128;
    const float* ej = emb + (j0 + b)*128;
    char* rowp = tile + t*512;
    int rs = (t & 7) << 4;
    if (cg < 4) {
      #pragma unroll
      for (int q = 0; q < 4; ++q) {
        int ce = cg*32 + q*8;                    // element col 0..127 (diff part)
        float4 x0 = *(const float4*)(ei + ce);
        float4 x1 = *(const float4*)(ei + ce + 4);
        float4 y0 = *(const float4*)(ej + ce);
        float4 y1 = *(const float4*)(ej + ce + 4);
        uint4 pk;
        pk.x = (u32)f2bf(x0.x - y0.x) | ((u32)f2bf(x0.y - y0.y) << 16);
        pk.y = (u32)f2bf(x0.z - y0.z) | ((u32)f2bf(x0.w - y0.w) << 16);
        pk.z = (u32)f2bf(x1.x - y1.x) | ((u32)f2bf(x1.y - y1.y) << 16);
        pk.w = (u32)f2bf(x1.z - y1.z) | ((u32)f2bf(x1.w - y1.w) << 16);
        *(uint4*)(rowp + ((ce*2) ^ rs)) = pk;
      }
    } else {
      #pragma unroll
      for (int q = 0; q < 4; ++q) {
        int ce = cg*32 + q*8;                    // element col 128..255 (prod part)
        int cs = ce - 128;
        float4 x0 = *(const float4*)(ei + cs);
        float4 x1 = *(const float4*)(ei + cs + 4);
        float4 y0 = *(const float4*)(ej + cs);
        float4 y1 = *(const float4*)(ej + cs + 4);
        uint4 pk;
        pk.x = (u32)f2bf(x0.x * y0.x) | ((u32)f2bf(x0.y * y0.y) << 16);
        pk.y = (u32)f2bf(x0.z * y0.z) | ((u32)f2bf(x0.w * y0.w) << 16);
        pk.z = (u32)f2bf(x1.x * y1.x) | ((u32)f2bf(x1.y * y1.y) << 16);
        pk.w = (u32)f2bf(x1.z * y1.z) | ((u32)f2bf(x1.w * y1.w) << 16);
        *(uint4*)(rowp + ((ce*2) ^ rs)) = pk;
      }
    }
  }
  sb1[tid] = b1v[tid];
  sgm[tid] = gammav[tid];
  sbt[tid] = betav[tid];
  if (tid < 256) { sb2[tid] = b2v[tid]; sw3[tid] = w3v[tid]; }
  __syncthreads();

  // ---- GEMM1: A1[64x256] @ W1[256x512]; wave owns 64-col stripe ----
  f32x4 acc1[4][4];
  #pragma unroll
  for (int m = 0; m < 4; ++m)
    #pragma unroll
    for (int n = 0; n < 4; ++n)
      acc1[m][n] = (f32x4){0.f, 0.f, 0.f, 0.f};

  const u16* w1p = W1t + (wave*64 + llo)*256 + lhi*8;
  #pragma unroll
  for (int kb = 0; kb < 8; ++kb) {
    bf16x8 af[4], bfr[4];
    #pragma unroll
    for (int m = 0; m < 4; ++m)
      af[m] = *(const bf16x8*)(tile + (m*16 + llo)*512 + ((kb*64 + lhi*16) ^ sw));
    #pragma unroll
    for (int n = 0; n < 4; ++n)
      bfr[n] = *(const bf16x8*)(w1p + n*4096 + kb*32);
    #pragma unroll
    for (int m = 0; m < 4; ++m)
      #pragma unroll
      for (int n = 0; n < 4; ++n)
        acc1[m][n] = __builtin_amdgcn_mfma_f32_16x16x32_bf16(af[m], bfr[n], acc1[m][n], 0, 0, 0);
  }

  // ---- epilogue1: +b1, relu, LN partial stats ----
  #pragma unroll
  for (int m = 0; m < 4; ++m) {
    #pragma unroll
    for (int q = 0; q < 4; ++q) {
      int r = m*16 + lhi*4 + q;
      float sum = 0.f, sq = 0.f;
      #pragma unroll
      for (int n = 0; n < 4; ++n) {
        int col = wave*64 + n*16 + llo;
        float v = acc1[m][n][q] + sb1[col];
        v = fmaxf(v, 0.f);
        acc1[m][n][q] = v;
        sum += v;
        sq  += v*v;
      }
      #pragma unroll
      for (int off = 1; off < 16; off <<= 1) {
        sum += __shfl_xor(sum, off, 64);
        sq  += __shfl_xor(sq,  off, 64);
      }
      if (llo == 0) { psum[r*8 + wave] = sum; psq[r*8 + wave] = sq; }
    }
  }
  __syncthreads();
  if (tid < 64) {
    float s = 0.f, ss = 0.f;
    #pragma unroll
    for (int w = 0; w < 8; ++w) { s += psum[tid*8 + w]; ss += psq[tid*8 + w]; }
    float mu  = s * (1.f/512.f);
    float var = ss * (1.f/512.f) - mu*mu;
    smu[tid]  = mu;
    ssin[tid] = rsqrtf(var + EPSV);
  }
  __syncthreads();

  // ---- normalize -> h1n bf16, XOR-swizzled [64][512] (1024B rows), over A1 region ----
  #pragma unroll
  for (int m = 0; m < 4; ++m) {
    #pragma unroll
    for (int q = 0; q < 4; ++q) {
      int r = m*16 + lhi*4 + q;
      int rs = (r & 7) << 4;
      float mu = smu[r], si = ssin[r];
      char* rowp = tile + r*1024;
      #pragma unroll
      for (int n = 0; n < 4; ++n) {
        int col = wave*64 + n*16 + llo;
        float v = (acc1[m][n][q] - mu) * si * sgm[col] + sbt[col];
        *(u16*)(rowp + ((col*2) ^ rs)) = f2bf(v);
      }
    }
  }
  __syncthreads();

  // ---- GEMM2: h1n[64x512] @ W2[512x256]; wave owns 32-col stripe ----
  f32x4 acc2[4][2];
  #pragma unroll
  for (int m = 0; m < 4; ++m) { acc2[m][0] = (f32x4){0,0,0,0}; acc2[m][1] = (f32x4){0,0,0,0}; }

  const u16* w2p = W2t + (wave*32 + llo)*512 + lhi*8;
  #pragma unroll 4
  for (int kb = 0; kb < 16; ++kb) {
    bf16x8 af[4], bfr[2];
    #pragma unroll
    for (int m = 0; m < 4; ++m)
      af[m] = *(const bf16x8*)(tile + (m*16 + llo)*1024 + ((kb*64 + lhi*16) ^ sw));
    #pragma unroll
    for (int n = 0; n < 2; ++n)
      bfr[n] = *(const bf16x8*)(w2p + n*8192 + kb*32);
    #pragma unroll
    for (int m = 0; m < 4; ++m)
      #pragma unroll
      for (int n = 0; n < 2; ++n)
        acc2[m][n] = __builtin_amdgcn_mfma_f32_16x16x32_bf16(af[m], bfr[n], acc2[m][n], 0, 0, 0);
  }

  // ---- epilogue2: +b2, relu, dot W3, reduce per row ----
  #pragma unroll
  for (int m = 0; m < 4; ++m) {
    #pragma unroll
    for (int q = 0; q < 4; ++q) {
      int r = m*16 + lhi*4 + q;
      float s = 0.f;
      #pragma unroll
      for (int n = 0; n < 2; ++n) {
        int col = wave*32 + n*16 + llo;
        float v = acc2[m][n][q] + sb2[col];
        v = fmaxf(v, 0.f);
        s += v * sw3[col];
      }
      #pragma unroll
      for (int off = 1; off < 16; off <<= 1) s += __shfl_xor(s, off, 64);
      if (llo == 0) psum[r*8 + wave] = s;
    }
  }
  __syncthreads();
  if (tid < 64) {
    float s = 0.f;
    #pragma unroll
    for (int w = 0; w < 8; ++w) s += psum[tid*8 + w];
    float logit = s + b3v[0];
    int a = tid >> 3, b = tid & 7;
    int i = i0 + a, j = j0 + b;
    if (i < j) {
      int eidx = i*(2*NN - i - 1)/2 + (j - i - 1);
      out[eidx] = logit;
      out[ETOT + 2*eidx]     = (float)i;
      out[ETOT + 2*eidx + 1] = (float)j;
    }
  }
}

extern "C" void kernel_launch(void* const* d_in, const int* in_sizes, int n_in,
                              void* d_out, int out_size, void* d_ws, size_t ws_size,
                              hipStream_t stream) {
  const float* emb   = (const float*)d_in[0];
  const float* W1    = (const float*)d_in[1];
  const float* b1    = (const float*)d_in[2];
  const float* gamma = (const float*)d_in[3];
  const float* beta  = (const float*)d_in[4];
  const float* W2    = (const float*)d_in[5];
  const float* b2    = (const float*)d_in[6];
  const float* W3    = (const float*)d_in[7];
  const float* b3    = (const float*)d_in[8];

  char* ws  = (char*)d_ws;
  u16* W1t = (u16*)ws;                       // 512*256*2 = 256 KiB
  u16* W2t = (u16*)(ws + 512*256*2);         // 256*512*2 = 256 KiB

  (void)hipFuncSetAttribute((const void*)edge_main,
                            hipFuncAttributeMaxDynamicSharedMemorySize, L_TOTAL);

  prep_wt<<<512, 256, 0, stream>>>(W1, W2, W1t, W2t);
  edge_main<<<8256, 512, L_TOTAL, stream>>>(emb, b1, gamma, beta, b2, W3, b3,
                                            W1t, W2t, (float*)d_out);
}